// Round 9
// baseline (217.431 us; speedup 1.0000x reference)
//
#include <hip/hip_runtime.h>
#include <hip/hip_fp16.h>
#include <cstdint>
#include <cstddef>

#define BB 4
#define CC 256
#define NN 4096
#define EPS_NORM 2.220446049250313e-16f
#define EPS_MIN 1e-5f

typedef __attribute__((ext_vector_type(8))) short short8;
typedef __attribute__((ext_vector_type(4))) float floatx4;
typedef __attribute__((ext_vector_type(4))) unsigned int uint4v;
typedef __attribute__((ext_vector_type(2))) _Float16 half2v;

__device__ __forceinline__ unsigned fmap(float f) {
    unsigned u = __float_as_uint(f);
    return (u & 0x80000000u) ? ~u : (u | 0x80000000u);
}
__device__ __forceinline__ float funmap(unsigned u) {
    return (u & 0x80000000u) ? __uint_as_float(u ^ 0x80000000u) : __uint_as_float(~u);
}
__device__ __forceinline__ unsigned short f2bf(float f) {
    unsigned u = __float_as_uint(f);
    u += 0x7FFFu + ((u >> 16) & 1u);   // RNE
    return (unsigned short)(u >> 16);
}
__device__ __forceinline__ void async_cp16(const void* g, void* l) {
    __builtin_amdgcn_global_load_lds(
        (const __attribute__((address_space(1))) unsigned int*)g,
        (__attribute__((address_space(3))) unsigned int*)l, 16, 0, 0);
}

// ---- K1: per-channel spatial mean of Y (float4) + init sums ---------------
__global__ void kmean(const float* __restrict__ Y, float* __restrict__ ymean,
                      float* __restrict__ sums) {
    if (blockIdx.x == 0 && threadIdx.x < BB) sums[threadIdx.x] = 0.f;
    int bc = blockIdx.x;  // b*CC + c
    const float4* p = (const float4*)(Y + (size_t)bc * NN);
    float s = 0.f;
    for (int k = threadIdx.x; k < NN / 4; k += 256) {
        float4 v = p[k];
        s += (v.x + v.y) + (v.z + v.w);
    }
    __shared__ float red[256];
    red[threadIdx.x] = s; __syncthreads();
    for (int st = 128; st > 0; st >>= 1) {
        if (threadIdx.x < st) red[threadIdx.x] += red[threadIdx.x + st];
        __syncthreads();
    }
    if (threadIdx.x == 0) ymean[bc] = red[0] * (1.0f / NN);
}

// ------- K2: fused norm + normalize + transpose -> bf16 [B,N,C] -------------
__global__ __launch_bounds__(256)
void kfuse(const float* __restrict__ X, const float* __restrict__ Y,
           const float* __restrict__ ymean,
           unsigned short* __restrict__ XnT, unsigned short* __restrict__ YnT) {
    int b = blockIdx.y >> 1, which = blockIdx.y & 1;
    const float* src = which ? Y : X;
    unsigned short* dst = which ? YnT : XnT;
    int n0 = blockIdx.x * 64;
    int tx = threadIdx.x & 63, ty = threadIdx.x >> 6;
    __shared__ float mean_s[CC];
    __shared__ float red[4][64];
    __shared__ float invn[64];
    __shared__ float tile[64][65];
    mean_s[threadIdx.x] = ymean[b * CC + threadIdx.x];
    __syncthreads();
    float vreg[64];
    float s = 0.f;
    #pragma unroll
    for (int k = 0; k < 64; ++k) {
        int c = ty + 4 * k;
        float v = src[(((size_t)b * CC + c) << 12) + n0 + tx] - mean_s[c];
        vreg[k] = v;
        s += v * v;
    }
    red[ty][tx] = s; __syncthreads();
    if (ty == 0) {
        float t = red[0][tx] + red[1][tx] + red[2][tx] + red[3][tx];
        invn[tx] = 1.0f / (sqrtf(t) + EPS_NORM);
    }
    __syncthreads();
    float inv = invn[tx];
    for (int cb = 0; cb < 4; ++cb) {
        if (cb) __syncthreads();
        #pragma unroll
        for (int kk = 0; kk < 16; ++kk) {
            tile[4 * kk + ty][tx] = vreg[cb * 16 + kk] * inv;
        }
        __syncthreads();
        #pragma unroll
        for (int it = 0; it < 16; ++it) {
            int nl = ty + it * 4;
            dst[((size_t)(b * NN + n0 + nl)) * CC + cb * 64 + tx] = f2bf(tile[tx][nl]);
        }
    }
}

// ---------------- init accumulators (recompute fallback only) ----------------
__global__ void kinit(unsigned* __restrict__ rowminU, float* __restrict__ rowsum,
                      unsigned* __restrict__ colmaxU) {
    int idx = blockIdx.x * 256 + threadIdx.x;
    rowminU[idx] = 0xFF800000u;
    rowsum[idx] = 0.f;
    colmaxU[idx] = 0x007FFFFFu;
}

// -------- GEMM core: s = A.B^T, XOR-swizzled async-staged LDS ---------------
// MODE 0: store s fp16 via LDS-staged coalesced writes (acc consumed once,
//         no reductions here — reductions live in kstats, R5-R7 lesson).
// MODE 1: atomic row-min.  MODE 2: atomic row-sum exp.  MODE 3: col-max.
template <int MODE>
__global__ __launch_bounds__(256, 4)
void kgemm(const unsigned short* __restrict__ Aptr, const unsigned short* __restrict__ Bptr,
           __half* __restrict__ dOut, size_t dstride,
           const float* __restrict__ rowA, const float* __restrict__ rowB,
           unsigned* __restrict__ rowminU, float* __restrict__ rowsum,
           unsigned* __restrict__ colmaxU) {
    int b = blockIdx.z;
    int i0 = blockIdx.y * 128, j0 = blockIdx.x * 128;
    int tid = threadIdx.x, lane = tid & 63, wave = tid >> 6;
    int wm = wave >> 1, wn = wave & 1, l15 = lane & 15, quad = lane >> 4;
    __shared__ unsigned short smem[17408];   // staging 32768 B | fp16 tile 128x136
    unsigned short* As = smem;
    unsigned short* Bs = smem + 128 * 64;
    floatx4 acc[4][4];
    #pragma unroll
    for (int ms = 0; ms < 4; ++ms)
        #pragma unroll
        for (int ns = 0; ns < 4; ++ns) acc[ms][ns] = (floatx4){0.f, 0.f, 0.f, 0.f};

    const unsigned short* gA = Aptr + (size_t)b * NN * CC + (size_t)i0 * CC;
    const unsigned short* gB = Bptr + (size_t)b * NN * CC + (size_t)j0 * CC;
    int rl = lane >> 3, pos = lane & 7;
    int cb = pos ^ (rl & 7);
    const unsigned short* gAl = gA + (size_t)(wave * 32 + rl) * CC + cb * 8;
    const unsigned short* gBl = gB + (size_t)(wave * 32 + rl) * CC + cb * 8;
    unsigned short* lA = As + (wave * 32) * 64;
    unsigned short* lB = Bs + (wave * 32) * 64;

    for (int kc = 0; kc < CC; kc += 64) {
        #pragma unroll
        for (int seg = 0; seg < 4; ++seg) {
            async_cp16(gAl + (size_t)seg * 8 * CC + kc, lA + seg * 8 * 64);
            async_cp16(gBl + (size_t)seg * 8 * CC + kc, lB + seg * 8 * 64);
        }
        __syncthreads();
        #pragma unroll
        for (int kk = 0; kk < 64; kk += 32) {
            short8 af[4], bf[4];
            int sw = (quad + (kk >> 3)) ^ (l15 & 7);
            #pragma unroll
            for (int s = 0; s < 4; ++s) {
                af[s] = *(const short8*)&As[(wm * 64 + s * 16 + l15) * 64 + (sw << 3)];
                bf[s] = *(const short8*)&Bs[(wn * 64 + s * 16 + l15) * 64 + (sw << 3)];
            }
            #pragma unroll
            for (int ms = 0; ms < 4; ++ms)
                #pragma unroll
                for (int ns = 0; ns < 4; ++ns)
                    acc[ms][ns] = __builtin_amdgcn_mfma_f32_16x16x32_bf16(af[ms], bf[ns], acc[ms][ns], 0, 0, 0);
        }
        __syncthreads();
    }

    int ibase = i0 + wm * 64, jbase = j0 + wn * 64;
    if (MODE == 0) {
        __half* tile = (__half*)smem;
        #pragma unroll
        for (int ms = 0; ms < 4; ++ms)
            #pragma unroll
            for (int r = 0; r < 4; ++r) {
                int il = wm * 64 + ms * 16 + quad * 4 + r;
                #pragma unroll
                for (int ns = 0; ns < 4; ++ns)
                    tile[il * 136 + wn * 64 + ns * 16 + l15] = __float2half(acc[ms][ns][r]);
            }
        __syncthreads();
        __half* dB = dOut + (size_t)b * dstride;
        #pragma unroll
        for (int it = 0; it < 8; ++it) {
            int idx = tid + it * 256;
            int row = idx >> 4, col = (idx & 15) * 8;
            *(uint4v*)&dB[(size_t)(i0 + row) * NN + j0 + col] =
                *(const uint4v*)&tile[row * 136 + col];
        }
    } else if (MODE == 1) {
        #pragma unroll
        for (int ms = 0; ms < 4; ++ms)
            #pragma unroll
            for (int r = 0; r < 4; ++r) {
                float m = 1e30f;
                #pragma unroll
                for (int ns = 0; ns < 4; ++ns) m = fminf(m, 1.0f - acc[ms][ns][r]);
                m = fminf(m, __shfl_xor(m, 1)); m = fminf(m, __shfl_xor(m, 2));
                m = fminf(m, __shfl_xor(m, 4)); m = fminf(m, __shfl_xor(m, 8));
                if (l15 == 0) {
                    int i = ibase + ms * 16 + quad * 4 + r;
                    atomicMin(&rowminU[b * NN + i], fmap(m));
                }
            }
    } else if (MODE == 2) {
        #pragma unroll
        for (int ms = 0; ms < 4; ++ms)
            #pragma unroll
            for (int r = 0; r < 4; ++r) {
                int i = ibase + ms * 16 + quad * 4 + r;
                float al = rowA[b * NN + i];
                float s = 0.f;
                #pragma unroll
                for (int ns = 0; ns < 4; ++ns) s += __expf(10.0f - al * (1.0f - acc[ms][ns][r]));
                s += __shfl_xor(s, 1); s += __shfl_xor(s, 2);
                s += __shfl_xor(s, 4); s += __shfl_xor(s, 8);
                if (l15 == 0) atomicAdd(&rowsum[b * NN + i], s);
            }
    } else {  // MODE 3
        float cm[4] = {-1e30f, -1e30f, -1e30f, -1e30f};
        #pragma unroll
        for (int ms = 0; ms < 4; ++ms)
            #pragma unroll
            for (int r = 0; r < 4; ++r) {
                int i = ibase + ms * 16 + quad * 4 + r;
                float al = rowA[b * NN + i], bl = rowB[b * NN + i];
                #pragma unroll
                for (int ns = 0; ns < 4; ++ns) {
                    float t = bl - al * (1.0f - acc[ms][ns][r]);
                    cm[ns] = fmaxf(cm[ns], t);
                }
            }
        #pragma unroll
        for (int ns = 0; ns < 4; ++ns) {
            float v = cm[ns];
            v = fmaxf(v, __shfl_xor(v, 16)); v = fmaxf(v, __shfl_xor(v, 32));
            if (quad == 0) {
                int j = jbase + ns * 16 + l15;
                atomicMax(&colmaxU[b * NN + j], fmap(v));
            }
        }
    }
}

// ------- fused row-stats + column-max partials. One block = 16 rows. --------
// Pass A: per-row max of s via packed fp16 max (dmin = 1 - smax).
// Pass B: sum exp((10-a) + a*s).  Pass C: per-column max of t = gam + a*s.
__global__ __launch_bounds__(256, 2)
void kstats(const __half* __restrict__ smat, size_t dBatch,
            float* __restrict__ partial, size_t pBatch) {
    int b = blockIdx.y, rg = blockIdx.x;
    const __half* base = smat + (size_t)b * dBatch + (size_t)rg * 16 * NN;
    float* pout = partial + (size_t)b * pBatch + (size_t)rg * NN;
    int t = threadIdx.x, wv = t >> 6, ln = t & 63;
    uint4v v0[16], v1[16];
    #pragma unroll
    for (int r = 0; r < 16; ++r) {
        v0[r] = *(const uint4v*)&base[(size_t)r * NN + t * 8];
        v1[r] = *(const uint4v*)&base[(size_t)r * NN + 2048 + t * 8];
    }
    __shared__ float wred[16][4];
    __shared__ float alphaS[16], gamS[16];
    // pass A: per-row max of s, packed fp16
    #pragma unroll
    for (int r = 0; r < 16; ++r) {
        half2v m2 = __builtin_bit_cast(half2v, v0[r][0]);
        #pragma unroll
        for (int e = 1; e < 4; ++e)
            m2 = __builtin_elementwise_max(m2, __builtin_bit_cast(half2v, v0[r][e]));
        #pragma unroll
        for (int e = 0; e < 4; ++e)
            m2 = __builtin_elementwise_max(m2, __builtin_bit_cast(half2v, v1[r][e]));
        float mx = fmaxf((float)m2[0], (float)m2[1]);
        mx = fmaxf(mx, __shfl_xor(mx, 1));  mx = fmaxf(mx, __shfl_xor(mx, 2));
        mx = fmaxf(mx, __shfl_xor(mx, 4));  mx = fmaxf(mx, __shfl_xor(mx, 8));
        mx = fmaxf(mx, __shfl_xor(mx, 16)); mx = fmaxf(mx, __shfl_xor(mx, 32));
        if (ln == 0) wred[r][wv] = mx;
    }
    __syncthreads();
    if (t < 16) {
        float mx = fmaxf(fmaxf(wred[t][0], wred[t][1]), fmaxf(wred[t][2], wred[t][3]));
        alphaS[t] = 10.0f / ((1.0f - mx) + EPS_MIN);
    }
    __syncthreads();
    // pass B: sum of exp((10-a) + a*s)
    #pragma unroll
    for (int r = 0; r < 16; ++r) {
        float a = alphaS[r], c = 10.0f - a;
        float s = 0.f;
        #pragma unroll
        for (int e = 0; e < 4; ++e) {
            float2 f0 = __half22float2(__builtin_bit_cast(__half2, v0[r][e]));
            float2 f1 = __half22float2(__builtin_bit_cast(__half2, v1[r][e]));
            s += __expf(fmaf(a, f0.x, c)) + __expf(fmaf(a, f0.y, c));
            s += __expf(fmaf(a, f1.x, c)) + __expf(fmaf(a, f1.y, c));
        }
        s += __shfl_xor(s, 1);  s += __shfl_xor(s, 2);  s += __shfl_xor(s, 4);
        s += __shfl_xor(s, 8);  s += __shfl_xor(s, 16); s += __shfl_xor(s, 32);
        if (ln == 0) wred[r][wv] = s;
    }
    __syncthreads();
    if (t < 16) {
        float sum = wred[t][0] + wred[t][1] + wred[t][2] + wred[t][3];
        gamS[t] = (10.0f - logf(sum)) - alphaS[t];   // t_ij = gam + a*s
    }
    __syncthreads();
    // pass C: per-column max over the 16 rows
    float pm0[8], pm1[8];
    #pragma unroll
    for (int e = 0; e < 8; ++e) { pm0[e] = -1e30f; pm1[e] = -1e30f; }
    #pragma unroll
    for (int r = 0; r < 16; ++r) {
        float a = alphaS[r], g = gamS[r];
        #pragma unroll
        for (int e = 0; e < 4; ++e) {
            float2 f0 = __half22float2(__builtin_bit_cast(__half2, v0[r][e]));
            float2 f1 = __half22float2(__builtin_bit_cast(__half2, v1[r][e]));
            pm0[2 * e]     = fmaxf(pm0[2 * e],     fmaf(a, f0.x, g));
            pm0[2 * e + 1] = fmaxf(pm0[2 * e + 1], fmaf(a, f0.y, g));
            pm1[2 * e]     = fmaxf(pm1[2 * e],     fmaf(a, f1.x, g));
            pm1[2 * e + 1] = fmaxf(pm1[2 * e + 1], fmaf(a, f1.y, g));
        }
    }
    *(float4*)&pout[t * 8]            = make_float4(pm0[0], pm0[1], pm0[2], pm0[3]);
    *(float4*)&pout[t * 8 + 4]        = make_float4(pm0[4], pm0[5], pm0[6], pm0[7]);
    *(float4*)&pout[2048 + t * 8]     = make_float4(pm1[0], pm1[1], pm1[2], pm1[3]);
    *(float4*)&pout[2048 + t * 8 + 4] = make_float4(pm1[4], pm1[5], pm1[6], pm1[7]);
}

// ------- reduce partials: colmax over rowgroups -> exp -> sum per batch -----
__global__ __launch_bounds__(1024)
void kred1(const float* __restrict__ partial, float* __restrict__ sums) {
    int b = blockIdx.y;
    int jl = threadIdx.x & 255;
    int j = blockIdx.x * 256 + jl;
    int slice = threadIdx.x >> 8;
    const float* p = partial + ((size_t)b * 256 + slice * 64) * NN + j;
    float m = -1e30f;
    #pragma unroll 4
    for (int pb = 0; pb < 64; ++pb) m = fmaxf(m, p[(size_t)pb * NN]);
    __shared__ float sl[4][256];
    sl[slice][jl] = m;
    __syncthreads();
    __shared__ float red[256];
    if (threadIdx.x < 256) {
        float mm = fmaxf(fmaxf(sl[0][threadIdx.x], sl[1][threadIdx.x]),
                         fmaxf(sl[2][threadIdx.x], sl[3][threadIdx.x]));
        red[threadIdx.x] = __expf(mm);
    }
    __syncthreads();
    for (int st = 128; st > 0; st >>= 1) {
        if (threadIdx.x < st) red[threadIdx.x] += red[threadIdx.x + st];
        __syncthreads();
    }
    if (threadIdx.x == 0) atomicAdd(&sums[b], red[0]);
}

__global__ void kfinal2(const float* __restrict__ sums, float* __restrict__ out) {
    int t = threadIdx.x;
    if (t < BB) out[t] = logf((float)NN) - logf(sums[t]);
}

// ---------------- recompute path helpers ----------------
__global__ void kalpha(const unsigned* __restrict__ rowminU, float* __restrict__ rowA) {
    int idx = blockIdx.x * 256 + threadIdx.x;
    rowA[idx] = 10.0f / (funmap(rowminU[idx]) + EPS_MIN);
}
__global__ void kbeta(const float* __restrict__ rowsum, float* __restrict__ rowB) {
    int idx = blockIdx.x * 256 + threadIdx.x;
    rowB[idx] = 10.0f - logf(rowsum[idx]);
}
__global__ void kfinalR(const unsigned* __restrict__ colmaxU, float* __restrict__ out) {
    int b = blockIdx.x;
    float s = 0.f;
    for (int j = threadIdx.x; j < NN; j += 256) s += __expf(funmap(colmaxU[b * NN + j]));
    __shared__ float red[256];
    red[threadIdx.x] = s; __syncthreads();
    for (int st = 128; st > 0; st >>= 1) {
        if (threadIdx.x < st) red[threadIdx.x] += red[threadIdx.x + st];
        __syncthreads();
    }
    if (threadIdx.x == 0) out[b] = logf((float)NN) - logf(red[0]);
}

extern "C" void kernel_launch(void* const* d_in, const int* in_sizes, int n_in,
                              void* d_out, int out_size, void* d_ws, size_t ws_size,
                              hipStream_t stream) {
    const float* X = (const float*)d_in[0];
    const float* Y = (const float*)d_in[1];
    float* out = (float*)d_out;

    char* w = (char*)d_ws;
    float* ymean        = (float*)(w + 0);
    float* sums         = (float*)(w + 4096);
    float* rowA         = (float*)(w + 135168);
    float* rowB         = (float*)(w + 200704);
    unsigned* rowminU   = (unsigned*)(w + 266240);
    float* rowsum       = (float*)(w + 331776);
    unsigned* colmaxU   = (unsigned*)(w + 397312);
    unsigned short* XnT = (unsigned short*)(w + 462848);
    unsigned short* YnT = (unsigned short*)(w + 8851456);
    float* partialC     = (float*)(w + 17240064);   // 16,777,216 B (all batches)
    __half* dchunk      = (__half*)(w + 34017280);  // R*NN fp16 chunk
    const size_t base_need = 34017280;

    kmean<<<dim3(BB * CC), 256, 0, stream>>>(Y, ymean, sums);
    kfuse<<<dim3(NN / 64, BB * 2), 256, 0, stream>>>(X, Y, ymean, XnT, YnT);

    size_t avail = (ws_size > base_need) ? ws_size - base_need : 0;
    long Rl = (long)((avail / ((size_t)NN * 2)) / 128) * 128;
    int R = (Rl > NN) ? NN : (int)Rl;
    if (R >= 128) {
        // per-(batch,chunk) pipeline: kgemm writes d-chunk, kstats reads it
        // L3-warm (33.5 MB/batch << 256 MB L3) — d never round-trips HBM cold.
        for (int b = 0; b < BB; ++b) {
            for (int i0c = 0; i0c < NN; i0c += R) {
                int rows = (NN - i0c < R) ? (NN - i0c) : R;
                size_t boff = (size_t)b * NN + i0c;
                kgemm<0><<<dim3(NN / 128, rows / 128, 1), 256, 0, stream>>>(
                    XnT + boff * CC, YnT + (size_t)b * NN * CC, dchunk, 0,
                    rowA, rowB, rowminU, rowsum, colmaxU);
                kstats<<<dim3(rows / 16, 1), 256, 0, stream>>>(
                    dchunk, 0,
                    partialC + ((size_t)b * (NN / 16) + i0c / 16) * NN, 0);
            }
        }
        kred1<<<dim3(NN / 256, BB), 1024, 0, stream>>>(partialC, sums);
        kfinal2<<<dim3(1), 64, 0, stream>>>(sums, out);
    } else {
        // recompute fallback: 3 GEMM passes with fused atomic reductions
        kinit<<<dim3(BB * NN / 256), 256, 0, stream>>>(rowminU, rowsum, colmaxU);
        dim3 ggrid(NN / 128, NN / 128, BB);
        kgemm<1><<<ggrid, 256, 0, stream>>>(XnT, YnT, (__half*)dchunk, 0,
                                            rowA, rowB, rowminU, rowsum, colmaxU);
        kalpha<<<dim3(BB * NN / 256), 256, 0, stream>>>(rowminU, rowA);
        kgemm<2><<<ggrid, 256, 0, stream>>>(XnT, YnT, (__half*)dchunk, 0,
                                            rowA, rowB, rowminU, rowsum, colmaxU);
        kbeta<<<dim3(BB * NN / 256), 256, 0, stream>>>(rowsum, rowB);
        kgemm<3><<<ggrid, 256, 0, stream>>>(XnT, YnT, (__half*)dchunk, 0,
                                            rowA, rowB, rowminU, rowsum, colmaxU);
        kfinalR<<<dim3(BB), 256, 0, stream>>>(colmaxU, out);
    }
}

// Round 10
// 170.839 us; speedup vs baseline: 1.2727x; 1.2727x over previous
//
#include <hip/hip_runtime.h>
#include <hip/hip_fp16.h>
#include <cstdint>
#include <cstddef>

#define BB 4
#define CC 256
#define NN 4096
#define EPS_NORM 2.220446049250313e-16f
#define EPS_MIN 1e-5f

typedef __attribute__((ext_vector_type(8))) short short8;
typedef __attribute__((ext_vector_type(4))) float floatx4;
typedef __attribute__((ext_vector_type(4))) unsigned int uint4v;
typedef __attribute__((ext_vector_type(2))) _Float16 half2v;

__device__ __forceinline__ unsigned fmap(float f) {
    unsigned u = __float_as_uint(f);
    return (u & 0x80000000u) ? ~u : (u | 0x80000000u);
}
__device__ __forceinline__ float funmap(unsigned u) {
    return (u & 0x80000000u) ? __uint_as_float(u ^ 0x80000000u) : __uint_as_float(~u);
}
__device__ __forceinline__ unsigned short f2bf(float f) {
    unsigned u = __float_as_uint(f);
    u += 0x7FFFu + ((u >> 16) & 1u);   // RNE
    return (unsigned short)(u >> 16);
}
__device__ __forceinline__ void async_cp16(const void* g, void* l) {
    __builtin_amdgcn_global_load_lds(
        (const __attribute__((address_space(1))) unsigned int*)g,
        (__attribute__((address_space(3))) unsigned int*)l, 16, 0, 0);
}

// ---- K1: per-channel spatial mean of Y (float4) + init sums ---------------
__global__ void kmean(const float* __restrict__ Y, float* __restrict__ ymean,
                      float* __restrict__ sums) {
    if (blockIdx.x == 0 && threadIdx.x < BB) sums[threadIdx.x] = 0.f;
    int bc = blockIdx.x;  // b*CC + c
    const float4* p = (const float4*)(Y + (size_t)bc * NN);
    float s = 0.f;
    for (int k = threadIdx.x; k < NN / 4; k += 256) {
        float4 v = p[k];
        s += (v.x + v.y) + (v.z + v.w);
    }
    __shared__ float red[256];
    red[threadIdx.x] = s; __syncthreads();
    for (int st = 128; st > 0; st >>= 1) {
        if (threadIdx.x < st) red[threadIdx.x] += red[threadIdx.x + st];
        __syncthreads();
    }
    if (threadIdx.x == 0) ymean[bc] = red[0] * (1.0f / NN);
}

// ------- K2: fused norm + normalize + transpose -> bf16 [B,N,C] -------------
__global__ __launch_bounds__(256)
void kfuse(const float* __restrict__ X, const float* __restrict__ Y,
           const float* __restrict__ ymean,
           unsigned short* __restrict__ XnT, unsigned short* __restrict__ YnT) {
    int b = blockIdx.y >> 1, which = blockIdx.y & 1;
    const float* src = which ? Y : X;
    unsigned short* dst = which ? YnT : XnT;
    int n0 = blockIdx.x * 64;
    int tx = threadIdx.x & 63, ty = threadIdx.x >> 6;
    __shared__ float mean_s[CC];
    __shared__ float red[4][64];
    __shared__ float invn[64];
    __shared__ float tile[64][65];
    mean_s[threadIdx.x] = ymean[b * CC + threadIdx.x];
    __syncthreads();
    float vreg[64];
    float s = 0.f;
    #pragma unroll
    for (int k = 0; k < 64; ++k) {
        int c = ty + 4 * k;
        float v = src[(((size_t)b * CC + c) << 12) + n0 + tx] - mean_s[c];
        vreg[k] = v;
        s += v * v;
    }
    red[ty][tx] = s; __syncthreads();
    if (ty == 0) {
        float t = red[0][tx] + red[1][tx] + red[2][tx] + red[3][tx];
        invn[tx] = 1.0f / (sqrtf(t) + EPS_NORM);
    }
    __syncthreads();
    float inv = invn[tx];
    for (int cb = 0; cb < 4; ++cb) {
        if (cb) __syncthreads();
        #pragma unroll
        for (int kk = 0; kk < 16; ++kk) {
            tile[4 * kk + ty][tx] = vreg[cb * 16 + kk] * inv;
        }
        __syncthreads();
        #pragma unroll
        for (int it = 0; it < 16; ++it) {
            int nl = ty + it * 4;
            dst[((size_t)(b * NN + n0 + nl)) * CC + cb * 64 + tx] = f2bf(tile[tx][nl]);
        }
    }
}

// ---------------- init accumulators (recompute fallback only) ----------------
__global__ void kinit(unsigned* __restrict__ rowminU, float* __restrict__ rowsum,
                      unsigned* __restrict__ colmaxU) {
    int idx = blockIdx.x * 256 + threadIdx.x;
    rowminU[idx] = 0xFF800000u;
    rowsum[idx] = 0.f;
    colmaxU[idx] = 0x007FFFFFu;
}

// -------- GEMM core: s = A.B^T, XOR-swizzled async-staged LDS ---------------
// MODE 0: store s fp16 via LDS-staged coalesced writes (acc consumed once,
//         no reductions here — R5-R7 lesson).
// MODE 1: atomic row-min.  MODE 2: atomic row-sum exp.  MODE 3: col-max.
template <int MODE>
__global__ __launch_bounds__(256, 4)
void kgemm(const unsigned short* __restrict__ Aptr, const unsigned short* __restrict__ Bptr,
           __half* __restrict__ dOut, size_t dstride,
           const float* __restrict__ rowA, const float* __restrict__ rowB,
           unsigned* __restrict__ rowminU, float* __restrict__ rowsum,
           unsigned* __restrict__ colmaxU) {
    int b = blockIdx.z;
    int i0 = blockIdx.y * 128, j0 = blockIdx.x * 128;
    int tid = threadIdx.x, lane = tid & 63, wave = tid >> 6;
    int wm = wave >> 1, wn = wave & 1, l15 = lane & 15, quad = lane >> 4;
    __shared__ unsigned short smem[17408];   // staging 32768 B | fp16 tile 128x136
    unsigned short* As = smem;
    unsigned short* Bs = smem + 128 * 64;
    floatx4 acc[4][4];
    #pragma unroll
    for (int ms = 0; ms < 4; ++ms)
        #pragma unroll
        for (int ns = 0; ns < 4; ++ns) acc[ms][ns] = (floatx4){0.f, 0.f, 0.f, 0.f};

    const unsigned short* gA = Aptr + (size_t)b * NN * CC + (size_t)i0 * CC;
    const unsigned short* gB = Bptr + (size_t)b * NN * CC + (size_t)j0 * CC;
    int rl = lane >> 3, pos = lane & 7;
    int cb = pos ^ (rl & 7);
    const unsigned short* gAl = gA + (size_t)(wave * 32 + rl) * CC + cb * 8;
    const unsigned short* gBl = gB + (size_t)(wave * 32 + rl) * CC + cb * 8;
    unsigned short* lA = As + (wave * 32) * 64;
    unsigned short* lB = Bs + (wave * 32) * 64;

    for (int kc = 0; kc < CC; kc += 64) {
        #pragma unroll
        for (int seg = 0; seg < 4; ++seg) {
            async_cp16(gAl + (size_t)seg * 8 * CC + kc, lA + seg * 8 * 64);
            async_cp16(gBl + (size_t)seg * 8 * CC + kc, lB + seg * 8 * 64);
        }
        __syncthreads();
        #pragma unroll
        for (int kk = 0; kk < 64; kk += 32) {
            short8 af[4], bf[4];
            int sw = (quad + (kk >> 3)) ^ (l15 & 7);
            #pragma unroll
            for (int s = 0; s < 4; ++s) {
                af[s] = *(const short8*)&As[(wm * 64 + s * 16 + l15) * 64 + (sw << 3)];
                bf[s] = *(const short8*)&Bs[(wn * 64 + s * 16 + l15) * 64 + (sw << 3)];
            }
            #pragma unroll
            for (int ms = 0; ms < 4; ++ms)
                #pragma unroll
                for (int ns = 0; ns < 4; ++ns)
                    acc[ms][ns] = __builtin_amdgcn_mfma_f32_16x16x32_bf16(af[ms], bf[ns], acc[ms][ns], 0, 0, 0);
        }
        __syncthreads();
    }

    int ibase = i0 + wm * 64, jbase = j0 + wn * 64;
    if (MODE == 0) {
        __half* tile = (__half*)smem;
        #pragma unroll
        for (int ms = 0; ms < 4; ++ms)
            #pragma unroll
            for (int r = 0; r < 4; ++r) {
                int il = wm * 64 + ms * 16 + quad * 4 + r;
                #pragma unroll
                for (int ns = 0; ns < 4; ++ns)
                    tile[il * 136 + wn * 64 + ns * 16 + l15] = __float2half(acc[ms][ns][r]);
            }
        __syncthreads();
        __half* dB = dOut + (size_t)b * dstride;
        #pragma unroll
        for (int it = 0; it < 8; ++it) {
            int idx = tid + it * 256;
            int row = idx >> 4, col = (idx & 15) * 8;
            *(uint4v*)&dB[(size_t)(i0 + row) * NN + j0 + col] =
                *(const uint4v*)&tile[row * 136 + col];
        }
    } else if (MODE == 1) {
        #pragma unroll
        for (int ms = 0; ms < 4; ++ms)
            #pragma unroll
            for (int r = 0; r < 4; ++r) {
                float m = 1e30f;
                #pragma unroll
                for (int ns = 0; ns < 4; ++ns) m = fminf(m, 1.0f - acc[ms][ns][r]);
                m = fminf(m, __shfl_xor(m, 1)); m = fminf(m, __shfl_xor(m, 2));
                m = fminf(m, __shfl_xor(m, 4)); m = fminf(m, __shfl_xor(m, 8));
                if (l15 == 0) {
                    int i = ibase + ms * 16 + quad * 4 + r;
                    atomicMin(&rowminU[b * NN + i], fmap(m));
                }
            }
    } else if (MODE == 2) {
        #pragma unroll
        for (int ms = 0; ms < 4; ++ms)
            #pragma unroll
            for (int r = 0; r < 4; ++r) {
                int i = ibase + ms * 16 + quad * 4 + r;
                float al = rowA[b * NN + i];
                float s = 0.f;
                #pragma unroll
                for (int ns = 0; ns < 4; ++ns) s += __expf(10.0f - al * (1.0f - acc[ms][ns][r]));
                s += __shfl_xor(s, 1); s += __shfl_xor(s, 2);
                s += __shfl_xor(s, 4); s += __shfl_xor(s, 8);
                if (l15 == 0) atomicAdd(&rowsum[b * NN + i], s);
            }
    } else {  // MODE 3
        float cm[4] = {-1e30f, -1e30f, -1e30f, -1e30f};
        #pragma unroll
        for (int ms = 0; ms < 4; ++ms)
            #pragma unroll
            for (int r = 0; r < 4; ++r) {
                int i = ibase + ms * 16 + quad * 4 + r;
                float al = rowA[b * NN + i], bl = rowB[b * NN + i];
                #pragma unroll
                for (int ns = 0; ns < 4; ++ns) {
                    float t = bl - al * (1.0f - acc[ms][ns][r]);
                    cm[ns] = fmaxf(cm[ns], t);
                }
            }
        #pragma unroll
        for (int ns = 0; ns < 4; ++ns) {
            float v = cm[ns];
            v = fmaxf(v, __shfl_xor(v, 16)); v = fmaxf(v, __shfl_xor(v, 32));
            if (quad == 0) {
                int j = jbase + ns * 16 + l15;
                atomicMax(&colmaxU[b * NN + j], fmap(v));
            }
        }
    }
}

// ------- fused row-stats + column-max partials. One block = 16 rows. --------
// 512 threads: thread t owns cols [t*8, t*8+8) for all 16 rows (16 uint4v =
// 64 data VGPRs — half of the 256-thread version → lb(512,2) = 16 waves/CU,
// 2x the memory parallelism of R8's kstats).
__global__ __launch_bounds__(512, 2)
void kstats(const __half* __restrict__ smat, size_t dBatch,
            float* __restrict__ partial, size_t pBatch) {
    int b = blockIdx.y, rg = blockIdx.x;
    const __half* base = smat + (size_t)b * dBatch + (size_t)rg * 16 * NN;
    float* pout = partial + (size_t)b * pBatch + (size_t)rg * NN;
    int t = threadIdx.x, wv = t >> 6, ln = t & 63;
    uint4v v[16];
    #pragma unroll
    for (int r = 0; r < 16; ++r)
        v[r] = *(const uint4v*)&base[(size_t)r * NN + t * 8];
    __shared__ float wred[16][8];
    __shared__ float alphaS[16], gamS[16];
    // pass A: per-row max of s, packed fp16
    #pragma unroll
    for (int r = 0; r < 16; ++r) {
        half2v m2 = __builtin_bit_cast(half2v, v[r][0]);
        #pragma unroll
        for (int e = 1; e < 4; ++e)
            m2 = __builtin_elementwise_max(m2, __builtin_bit_cast(half2v, v[r][e]));
        float mx = fmaxf((float)m2[0], (float)m2[1]);
        mx = fmaxf(mx, __shfl_xor(mx, 1));  mx = fmaxf(mx, __shfl_xor(mx, 2));
        mx = fmaxf(mx, __shfl_xor(mx, 4));  mx = fmaxf(mx, __shfl_xor(mx, 8));
        mx = fmaxf(mx, __shfl_xor(mx, 16)); mx = fmaxf(mx, __shfl_xor(mx, 32));
        if (ln == 0) wred[r][wv] = mx;
    }
    __syncthreads();
    if (t < 16) {
        float mx = wred[t][0];
        #pragma unroll
        for (int k = 1; k < 8; ++k) mx = fmaxf(mx, wred[t][k]);
        alphaS[t] = 10.0f / ((1.0f - mx) + EPS_MIN);
    }
    __syncthreads();
    // pass B: sum of exp((10-a) + a*s)
    #pragma unroll
    for (int r = 0; r < 16; ++r) {
        float a = alphaS[r], c = 10.0f - a;
        float s = 0.f;
        #pragma unroll
        for (int e = 0; e < 4; ++e) {
            float2 f = __half22float2(__builtin_bit_cast(__half2, v[r][e]));
            s += __expf(fmaf(a, f.x, c)) + __expf(fmaf(a, f.y, c));
        }
        s += __shfl_xor(s, 1);  s += __shfl_xor(s, 2);  s += __shfl_xor(s, 4);
        s += __shfl_xor(s, 8);  s += __shfl_xor(s, 16); s += __shfl_xor(s, 32);
        if (ln == 0) wred[r][wv] = s;
    }
    __syncthreads();
    if (t < 16) {
        float sum = wred[t][0];
        #pragma unroll
        for (int k = 1; k < 8; ++k) sum += wred[t][k];
        gamS[t] = (10.0f - logf(sum)) - alphaS[t];   // t_ij = gam + a*s
    }
    __syncthreads();
    // pass C: per-column max over the 16 rows
    float pm[8];
    #pragma unroll
    for (int e = 0; e < 8; ++e) pm[e] = -1e30f;
    #pragma unroll
    for (int r = 0; r < 16; ++r) {
        float a = alphaS[r], g = gamS[r];
        #pragma unroll
        for (int e = 0; e < 4; ++e) {
            float2 f = __half22float2(__builtin_bit_cast(__half2, v[r][e]));
            pm[2 * e]     = fmaxf(pm[2 * e],     fmaf(a, f.x, g));
            pm[2 * e + 1] = fmaxf(pm[2 * e + 1], fmaf(a, f.y, g));
        }
    }
    *(float4*)&pout[t * 8]     = make_float4(pm[0], pm[1], pm[2], pm[3]);
    *(float4*)&pout[t * 8 + 4] = make_float4(pm[4], pm[5], pm[6], pm[7]);
}

// ------- reduce partials: colmax over rowgroups -> exp -> sum per batch -----
__global__ __launch_bounds__(1024)
void kred1(const float* __restrict__ partial, float* __restrict__ sums) {
    int b = blockIdx.y;
    int jl = threadIdx.x & 255;
    int j = blockIdx.x * 256 + jl;
    int slice = threadIdx.x >> 8;
    const float* p = partial + ((size_t)b * 256 + slice * 64) * NN + j;
    float m = -1e30f;
    #pragma unroll 4
    for (int pb = 0; pb < 64; ++pb) m = fmaxf(m, p[(size_t)pb * NN]);
    __shared__ float sl[4][256];
    sl[slice][jl] = m;
    __syncthreads();
    __shared__ float red[256];
    if (threadIdx.x < 256) {
        float mm = fmaxf(fmaxf(sl[0][threadIdx.x], sl[1][threadIdx.x]),
                         fmaxf(sl[2][threadIdx.x], sl[3][threadIdx.x]));
        red[threadIdx.x] = __expf(mm);
    }
    __syncthreads();
    for (int st = 128; st > 0; st >>= 1) {
        if (threadIdx.x < st) red[threadIdx.x] += red[threadIdx.x + st];
        __syncthreads();
    }
    if (threadIdx.x == 0) atomicAdd(&sums[b], red[0]);
}

__global__ void kfinal2(const float* __restrict__ sums, float* __restrict__ out) {
    int t = threadIdx.x;
    if (t < BB) out[t] = logf((float)NN) - logf(sums[t]);
}

// ---------------- recompute path helpers ----------------
__global__ void kalpha(const unsigned* __restrict__ rowminU, float* __restrict__ rowA) {
    int idx = blockIdx.x * 256 + threadIdx.x;
    rowA[idx] = 10.0f / (funmap(rowminU[idx]) + EPS_MIN);
}
__global__ void kbeta(const float* __restrict__ rowsum, float* __restrict__ rowB) {
    int idx = blockIdx.x * 256 + threadIdx.x;
    rowB[idx] = 10.0f - logf(rowsum[idx]);
}
__global__ void kfinalR(const unsigned* __restrict__ colmaxU, float* __restrict__ out) {
    int b = blockIdx.x;
    float s = 0.f;
    for (int j = threadIdx.x; j < NN; j += 256) s += __expf(funmap(colmaxU[b * NN + j]));
    __shared__ float red[256];
    red[threadIdx.x] = s; __syncthreads();
    for (int st = 128; st > 0; st >>= 1) {
        if (threadIdx.x < st) red[threadIdx.x] += red[threadIdx.x + st];
        __syncthreads();
    }
    if (threadIdx.x == 0) out[b] = logf((float)NN) - logf(red[0]);
}

extern "C" void kernel_launch(void* const* d_in, const int* in_sizes, int n_in,
                              void* d_out, int out_size, void* d_ws, size_t ws_size,
                              hipStream_t stream) {
    const float* X = (const float*)d_in[0];
    const float* Y = (const float*)d_in[1];
    float* out = (float*)d_out;

    char* w = (char*)d_ws;
    float* ymean        = (float*)(w + 0);
    float* sums         = (float*)(w + 4096);
    float* rowA         = (float*)(w + 135168);
    float* rowB         = (float*)(w + 200704);
    unsigned* rowminU   = (unsigned*)(w + 266240);
    float* rowsum       = (float*)(w + 331776);
    unsigned* colmaxU   = (unsigned*)(w + 397312);
    unsigned short* XnT = (unsigned short*)(w + 462848);
    unsigned short* YnT = (unsigned short*)(w + 8851456);
    __half* dmat        = (__half*)(w + 17240064);          // 134,217,728 B
    float* partialFull  = (float*)(w + 462848);             // reuse dead XnT/YnT
    const size_t full_need = 17240064 + (size_t)BB * NN * NN * 2;   // 151.5 MB

    kmean<<<dim3(BB * CC), 256, 0, stream>>>(Y, ymean, sums);
    kfuse<<<dim3(NN / 64, BB * 2), 256, 0, stream>>>(X, Y, ymean, XnT, YnT);

    if (ws_size >= full_need) {
        kgemm<0><<<dim3(NN / 128, NN / 128, BB), 256, 0, stream>>>(
            XnT, YnT, dmat, (size_t)NN * NN, rowA, rowB, rowminU, rowsum, colmaxU);
        kstats<<<dim3(NN / 16, BB), 512, 0, stream>>>(
            dmat, (size_t)NN * NN, partialFull, (size_t)(NN / 16) * NN);
        kred1<<<dim3(NN / 256, BB), 1024, 0, stream>>>(partialFull, sums);
        kfinal2<<<dim3(1), 64, 0, stream>>>(sums, out);
    } else {
        float* partialC = (float*)(w + 17240064);           // 16.78 MB
        __half* dchunk  = (__half*)(w + 34017280);
        size_t avail = (ws_size > 34017280) ? ws_size - 34017280 : 0;
        long Rl = (long)((avail / ((size_t)NN * 2)) / 128) * 128;
        int R = (Rl > NN) ? NN : (int)Rl;
        if (R >= 128) {
            for (int b = 0; b < BB; ++b) {
                for (int i0c = 0; i0c < NN; i0c += R) {
                    int rows = (NN - i0c < R) ? (NN - i0c) : R;
                    size_t boff = (size_t)b * NN + i0c;
                    kgemm<0><<<dim3(NN / 128, rows / 128, 1), 256, 0, stream>>>(
                        XnT + boff * CC, YnT + (size_t)b * NN * CC, dchunk, 0,
                        rowA, rowB, rowminU, rowsum, colmaxU);
                    kstats<<<dim3(rows / 16, 1), 512, 0, stream>>>(
                        dchunk, 0,
                        partialC + ((size_t)b * (NN / 16) + i0c / 16) * NN, 0);
                }
            }
            kred1<<<dim3(NN / 256, BB), 1024, 0, stream>>>(partialC, sums);
            kfinal2<<<dim3(1), 64, 0, stream>>>(sums, out);
        } else {
            // recompute fallback: 3 GEMM passes with fused atomic reductions
            kinit<<<dim3(BB * NN / 256), 256, 0, stream>>>(rowminU, rowsum, colmaxU);
            dim3 ggrid(NN / 128, NN / 128, BB);
            kgemm<1><<<ggrid, 256, 0, stream>>>(XnT, YnT, (__half*)dchunk, 0,
                                                rowA, rowB, rowminU, rowsum, colmaxU);
            kalpha<<<dim3(BB * NN / 256), 256, 0, stream>>>(rowminU, rowA);
            kgemm<2><<<ggrid, 256, 0, stream>>>(XnT, YnT, (__half*)dchunk, 0,
                                                rowA, rowB, rowminU, rowsum, colmaxU);
            kbeta<<<dim3(BB * NN / 256), 256, 0, stream>>>(rowsum, rowB);
            kgemm<3><<<ggrid, 256, 0, stream>>>(XnT, YnT, (__half*)dchunk, 0,
                                                rowA, rowB, rowminU, rowsum, colmaxU);
            kfinalR<<<dim3(BB), 256, 0, stream>>>(colmaxU, out);
        }
    }
}